// Round 1
// 28.661 us; speedup vs baseline: 1.1775x; 1.1775x over previous
//
#include <hip/hip_runtime.h>
#include <stdint.h>

#define NCLS 10
#define HID  512
#define KP   800      // 784 real + zero pad
#define BM   64
#define THREADS 768   // 12 waves: 8 consumer (GEMM) + 4 producer (x staging)
#define NBLK 256
#define YSTR 808      // x LDS row stride (shorts): 1616 B, 16B-aligned, conflict-minimal
#define HSTR 520      // h LDS row stride (r3-proven)

typedef __attribute__((ext_vector_type(8))) short short8;
typedef __attribute__((ext_vector_type(4))) float f32x4;

__device__ __forceinline__ unsigned short f2bf(float f) {
  union { float f; unsigned u; } v; v.f = f;
  unsigned r = v.u + 0x7fffu + ((v.u >> 16) & 1u);
  return (unsigned short)(r >> 16);
}
#define PK2(a, b) ((unsigned)f2bf(a) | ((unsigned)f2bf(b) << 16))

// Prep (r7/r8-proven, unchanged):
//  Weff[800][512] = conv composed into W1, bf16 frag-linear [25 kk32][32 nt][64 lane][8]
//  W2f bf16 frag-linear [16 kt][64 lane][8]
__global__ void prep_kernel(const float* __restrict__ W1, const float* __restrict__ cw,
                            const float* __restrict__ W2,
                            unsigned short* __restrict__ Wf, unsigned short* __restrict__ W2f) {
  int i = blockIdx.x * blockDim.x + threadIdx.x;
  const int total1 = KP * HID;               // 409600
  if (i < total1) {
    int k = i >> 9, n = i & 511;
    float s = 0.f;
    if (k < 784) {
      int iy = k / 28, ix = k - iy * 28;
#pragma unroll
      for (int ky = 0; ky < 3; ++ky) {
        int oy = iy - ky;
        if ((unsigned)oy < 26u) {
#pragma unroll
          for (int kx = 0; kx < 3; ++kx) {
            int ox = ix - kx;
            if ((unsigned)ox < 26u)
              s += cw[ky * 3 + kx] * W1[(oy * 26 + ox) * HID + n];
          }
        }
      }
    }
    int dst = (((k >> 5) * 32 + (n >> 4)) * 64 + ((k >> 3) & 3) * 16 + (n & 15)) * 8 + (k & 7);
    Wf[dst] = f2bf(s);
  } else if (i < total1 + 8192) {
    int i2 = i - total1;
    int k = i2 >> 4, n = i2 & 15;
    unsigned short v = 0;
    if (n < NCLS) v = f2bf(W2[k * NCLS + n]);
    int dst = ((k >> 5) * 64 + ((k >> 3) & 3) * 16 + n) * 8 + (k & 7);
    W2f[dst] = v;
  }
}

// K-chunks (kk units of 32): [0,7) [7,13) [13,19) [19,25)
//   chunk float-ranges: [0,224) [224,416) [416,608) [608,784)+pad
// Producers (waves 8..11) stage chunk c+1 while consumers (waves 0..7) GEMM chunk c.
// Chunks are disjoint LDS column ranges of one y tile -> only 1 barrier per chunk.
__global__ __launch_bounds__(THREADS, 3)
void main_kernel(const float* __restrict__ x, const unsigned short* __restrict__ Wf,
                 const float* __restrict__ b1, const unsigned short* __restrict__ W2f,
                 const float* __restrict__ b2, float* __restrict__ out) {
  __shared__ __align__(16) unsigned short y_lds[BM * YSTR];    // 103424 B (reused as h_lds)
  __shared__ float part_lds[32 * 256];                         // 32768 B (GEMM2 partials)

  const int tid  = threadIdx.x;
  const int lane = tid & 63;
  const int w    = tid >> 6;       // wave 0..11
  const int r0   = blockIdx.x * BM;
  const int row  = lane & 15;
  const int kg   = lane >> 4;      // 0..3
  const int wcol = w * 64;

  // ---- prologue: all threads stage chunk 0 (k in [0,224)) + zero pad ----
  for (int u = tid; u < BM * 28; u += THREADS) {     // 1792 units of 8 floats (32B)
    int r = u / 28, j = u - r * 28;
    const f32x4* p = (const f32x4*)(x + (size_t)(r0 + r) * 784 + j * 8);
    f32x4 v0 = p[0], v1 = p[1];
    uint4 d;
    d.x = PK2(v0[0], v0[1]); d.y = PK2(v0[2], v0[3]);
    d.z = PK2(v1[0], v1[1]); d.w = PK2(v1[2], v1[3]);
    *(uint4*)&y_lds[r * YSTR + j * 8] = d;
  }
  if (tid < BM * 2) {              // zero pad k in [784, 800)
    int r = tid >> 1, hf = tid & 1;
    uint4 z; z.x = z.y = z.z = z.w = 0u;
    *(uint4*)&y_lds[r * YSTR + 784 + hf * 8] = z;
  }
  __syncthreads();

  f32x4 acc1[4][4];
#pragma unroll
  for (int rt = 0; rt < 4; ++rt)
#pragma unroll
    for (int ct = 0; ct < 4; ++ct)
      acc1[rt][ct] = (f32x4){0.f, 0.f, 0.f, 0.f};

  // ---- pipelined GEMM1: [64 x 800] * [800 x 512]; wave w owns cols [w*64, w*64+64) ----
#pragma unroll
  for (int c = 0; c < 4; ++c) {
    if (w < 8) {
      const int kkS = (c == 0) ? 0 : (c == 1) ? 7 : (c == 2) ? 13 : 19;
      const int kkE = (c == 0) ? 7 : (c == 1) ? 13 : (c == 2) ? 19 : 25;
#pragma unroll
      for (int kk = kkS; kk < kkE; ++kk) {
        short8 bb[4], a[4];
#pragma unroll
        for (int ct = 0; ct < 4; ++ct)
          bb[ct] = *(const short8*)(Wf + ((size_t)((kk * 32 + w * 4 + ct) * 64) + lane) * 8);
#pragma unroll
        for (int rt = 0; rt < 4; ++rt)
          a[rt] = *(const short8*)&y_lds[(rt * 16 + row) * YSTR + kk * 32 + kg * 8];
#pragma unroll
        for (int rt = 0; rt < 4; ++rt)
#pragma unroll
          for (int ct = 0; ct < 4; ++ct)
            acc1[rt][ct] = __builtin_amdgcn_mfma_f32_16x16x32_bf16(a[rt], bb[ct], acc1[rt][ct], 0, 0, 0);
      }
    } else if (c < 3) {
      // producer waves stage chunk c+1: disjoint k-range, no hazard with chunk-c reads
      const int k0  = (c == 0) ? 224 : (c == 1) ? 416 : 608;
      const int upr = (c == 2) ? 22 : 24;       // 8-float units per row
      for (int u = tid - 512; u < BM * upr; u += 256) {
        int r = u / upr, j = u - r * upr;
        const f32x4* p = (const f32x4*)(x + (size_t)(r0 + r) * 784 + k0 + j * 8);
        f32x4 v0 = p[0], v1 = p[1];
        uint4 d;
        d.x = PK2(v0[0], v0[1]); d.y = PK2(v0[2], v0[3]);
        d.z = PK2(v1[0], v1[1]); d.w = PK2(v1[2], v1[3]);
        *(uint4*)&y_lds[r * YSTR + k0 + j * 8] = d;
      }
    }
    __syncthreads();
  }

  if (w < 8) {
    // ---- epilogue: h = relu(acc1 + b1) -> h_lds (bf16), reuse y_lds ----
    unsigned short* h_lds = y_lds;
    float b1v[4];
#pragma unroll
    for (int ct = 0; ct < 4; ++ct)
      b1v[ct] = b1[wcol + ct * 16 + row];

#pragma unroll
    for (int rt = 0; rt < 4; ++rt)
#pragma unroll
      for (int ct = 0; ct < 4; ++ct)
#pragma unroll
        for (int j = 0; j < 4; ++j) {
          int rr = rt * 16 + kg * 4 + j;
          int cc = wcol + ct * 16 + row;
          float hv = acc1[rt][ct][j] + b1v[ct];
          hv = hv > 0.f ? hv : 0.f;
          h_lds[rr * HSTR + cc] = f2bf(hv);
        }

    // ---- GEMM2 (MFMA): wave w k-slice [w*64, w*64+64) = exactly the cols it wrote,
    //      so no barrier needed (within-wave LDS dependency only) ----
    short8 b0  = *(const short8*)(W2f + ((size_t)(2 * w) * 64 + lane) * 8);
    short8 b1f = *(const short8*)(W2f + ((size_t)(2 * w + 1) * 64 + lane) * 8);
#pragma unroll
    for (int rt = 0; rt < 4; ++rt) {
      short8 a0 = *(const short8*)&h_lds[(rt * 16 + row) * HSTR + w * 64 + kg * 8];
      short8 a1 = *(const short8*)&h_lds[(rt * 16 + row) * HSTR + w * 64 + 32 + kg * 8];
      f32x4 p = (f32x4){0.f, 0.f, 0.f, 0.f};
      p = __builtin_amdgcn_mfma_f32_16x16x32_bf16(a0, b0, p, 0, 0, 0);
      p = __builtin_amdgcn_mfma_f32_16x16x32_bf16(a1, b1f, p, 0, 0, 0);
#pragma unroll
      for (int j = 0; j < 4; ++j)
        part_lds[(w * 4 + rt) * 256 + (kg * 4 + j) * 16 + row] = p[j];
    }
  }
  __syncthreads();

  // ---- reduce 8 wave-partials + bias, write out (640 outs, one per thread) ----
  if (tid < BM * NCLS) {
    int r  = tid / NCLS;
    int cc = tid - r * NCLS;
    float s = b2[cc];
#pragma unroll
    for (int w8 = 0; w8 < 8; ++w8)
      s += part_lds[(w8 * 4 + (r >> 4)) * 256 + (r & 15) * 16 + cc];
    out[(size_t)(r0 + r) * NCLS + cc] = s;
  }
}

extern "C" void kernel_launch(void* const* d_in, const int* in_sizes, int n_in,
                              void* d_out, int out_size, void* d_ws, size_t ws_size,
                              hipStream_t stream) {
  const float* x  = (const float*)d_in[0];
  const float* cw = (const float*)d_in[1];
  const float* W1 = (const float*)d_in[2];
  const float* b1 = (const float*)d_in[3];
  const float* W2 = (const float*)d_in[4];
  const float* b2 = (const float*)d_in[5];
  float* out = (float*)d_out;

  unsigned short* Wf  = (unsigned short*)d_ws;                     // 819200 B
  unsigned short* W2f = (unsigned short*)((char*)d_ws + 819200);   // 16384 B

  // prep: 409600 + 8192 = 417792 = 1632 * 256
  prep_kernel<<<1632, 256, 0, stream>>>(W1, cw, W2, Wf, W2f);
  main_kernel<<<NBLK, THREADS, 0, stream>>>(x, Wf, b1, W2f, b2, out);
}